// Round 1
// baseline (251.649 us; speedup 1.0000x reference)
//
#include <hip/hip_runtime.h>
#include <hip/hip_cooperative_groups.h>

namespace cg = cooperative_groups;

#define D_MODEL 128
#define NBANDS 12
#define NHEADS 2
#define HDIM 64
#define NCONSTS 364   // a[2] e[2] u[24] v[24] g[24] w[288]
#define NROWS (39 * D_MODEL)   // 4992 projected-row dot products
#define BLOCK 256
// softmax logit scale with log2(e) pre-folded: exp(x*0.125) == exp2(x*0.18033688)
#define LOGIT_SCALE 0.18033688011112042f

// ===========================================================================
// Fused cooperative kernel: all three phases in ONE launch.
//   Phase 1: inter[(m*13+c)*128+row]  (wave-per-row, grid-strided)
//   Phase 2: 364 consts, wave-per-const. HDIM==64 -> one element per lane,
//            coalesced 256B loads from L2-hot inter, 6-level shfl reduce.
//   Phase 3: one thread per (token, q), grid-strided.
// Two grid.sync()s replace two kernel-launch boundaries.
// ===========================================================================
__global__ __launch_bounds__(BLOCK, 4) void spectral_fused_kernel(
    const float* __restrict__ x,
    const float* __restrict__ w_embed, const float* __restrict__ b_embed,
    const float* __restrict__ band_pos,
    const float* __restrict__ Wq, const float* __restrict__ bq,
    const float* __restrict__ Wk, const float* __restrict__ bk,
    const float* __restrict__ Wv, const float* __restrict__ bv,
    const float* __restrict__ Wo, const float* __restrict__ bo,
    float* __restrict__ ws, float* __restrict__ out, int n_total)
{
    const int t      = threadIdx.x;
    const int lane   = t & 63;
    const int bwave  = t >> 6;
    const int nwaves = (int)(gridDim.x << 2);           // 4 waves/block
    const int gwave0 = (int)(blockIdx.x << 2) + bwave;

    float* inter  = ws;             // 4992 floats
    float* consts = ws + NROWS;     // 364 floats

    // ---------------- Phase 1: projected rows ----------------
    for (int g = gwave0; g < NROWS; g += nwaves) {
        const int mc  = g >> 7;          // 0..38 (wave-uniform)
        const int row = g & 127;
        const int m = mc / 13, c = mc - m * 13;
        const float* M    = (m == 0) ? Wq : (m == 1) ? Wk : Wv;
        const float* bias = (m == 0) ? bq : (m == 1) ? bk : bv;

        const float2 mv = reinterpret_cast<const float2*>(M + row * D_MODEL)[lane];
        float2 vv;
        if (c == 0) {
            vv = reinterpret_cast<const float2*>(w_embed)[lane];
        } else {
            const float2 be2 = reinterpret_cast<const float2*>(b_embed)[lane];
            const float2 bp2 = reinterpret_cast<const float2*>(band_pos + (c - 1) * D_MODEL)[lane];
            vv = make_float2(be2.x + bp2.x, be2.y + bp2.y);
        }
        float s = fmaf(mv.x, vv.x, mv.y * vv.y);
        #pragma unroll
        for (int off = 32; off; off >>= 1) s += __shfl_xor(s, off, 64);
        if (lane == 0) inter[g] = c ? (s + bias[row]) : s;
    }

    __threadfence();
    cg::this_grid().sync();

    // ---------------- Phase 2: 364 closed-form constants ----------------
    {
        const float* qv = inter;                  // [13][128]
        const float* kv = inter + 13 * D_MODEL;
        const float* vv = inter + 26 * D_MODEL;
        for (int idx = gwave0; idx < NCONSTS; idx += nwaves) {
            float pa, pb, scale = LOGIT_SCALE;
            if (idx < 2) {                                   // a_h
                pa = qv[idx * HDIM + lane];
                pb = kv[idx * HDIM + lane];
            } else if (idx < 4) {                            // e_h (no scale)
                const int h = idx - 2;
                pa = vv[h * HDIM + lane];
                pb = Wo[h * HDIM + lane];
                scale = 1.f;
            } else if (idx < 28) {                           // u_h[k]
                const int i = idx - 4, h = i / NBANDS, k = i - h * NBANDS;
                pa = qv[h * HDIM + lane];
                pb = kv[(1 + k) * D_MODEL + h * HDIM + lane];
            } else if (idx < 52) {                           // v_h[q]
                const int i = idx - 28, h = i / NBANDS, q = i - h * NBANDS;
                pa = qv[(1 + q) * D_MODEL + h * HDIM + lane];
                pb = kv[h * HDIM + lane];
            } else if (idx < 76) {                           // g_h[k] (no scale)
                const int i = idx - 52, h = i / NBANDS, k = i - h * NBANDS;
                pa = vv[(1 + k) * D_MODEL + h * HDIM + lane];
                pb = Wo[h * HDIM + lane];
                scale = 1.f;
            } else {                                         // w_h[q][k]
                const int i = idx - 76, h = i / (NBANDS * NBANDS);
                const int r = i - h * NBANDS * NBANDS;
                const int q = r / NBANDS, k = r - q * NBANDS;
                pa = qv[(1 + q) * D_MODEL + h * HDIM + lane];
                pb = kv[(1 + k) * D_MODEL + h * HDIM + lane];
            }
            float s = pa * pb;
            #pragma unroll
            for (int off = 32; off; off >>= 1) s += __shfl_xor(s, off, 64);
            if (lane == 0) consts[idx] = s * scale;
        }
    }

    __threadfence();
    cg::this_grid().sync();

    // ---------------- Phase 3: per-(token,q) main loop ----------------
    __shared__ float sc[NCONSTS];
    for (int i = t; i < NCONSTS; i += BLOCK) sc[i] = consts[i];
    __syncthreads();

    const float bo0   = bo[0];
    const int stride  = (int)gridDim.x * BLOCK;
    for (int tid = (int)blockIdx.x * BLOCK + t; tid < n_total; tid += stride) {
        const unsigned n = (unsigned)tid / 12u;   // magic-mul div
        const int q = tid - (int)n * 12;

        const float4* xin = reinterpret_cast<const float4*>(x + (size_t)n * NBANDS);
        const float4 p0 = xin[0], p1 = xin[1], p2 = xin[2];
        const float xb[NBANDS] = {p0.x,p0.y,p0.z,p0.w, p1.x,p1.y,p1.z,p1.w, p2.x,p2.y,p2.z,p2.w};
        const float xq = x[tid];   // == xb[q] without dynamic reg indexing

        float acc = bo0;
        #pragma unroll
        for (int h = 0; h < NHEADS; ++h) {
            const float a = sc[h];
            const float e = sc[2 + h];
            const float* u  = &sc[4  + h * NBANDS];
            const float vq  = sc[28 + h * NBANDS + q];
            const float* g  = &sc[52 + h * NBANDS];
            const float* wq = &sc[76 + h * NBANDS * NBANDS + q * NBANDS];
            const float coef = fmaf(a, xq, vq);
            float den = 0.f, num = 0.f;
            #pragma unroll
            for (int k = 0; k < NBANDS; ++k) {
                const float sv = fmaf(coef, xb[k], fmaf(u[k], xq, wq[k]));  // log2-domain logit
                const float p  = __builtin_amdgcn_exp2f(sv);
                den += p;
                num  = fmaf(p, fmaf(e, xb[k], g[k]), num);
            }
            acc = fmaf(num, __builtin_amdgcn_rcpf(den), acc);
        }
        out[tid] = xq + acc;
    }
}

// ===========================================================================
// Fallback path (proven 3-kernel version) in case cooperative launch is
// unavailable under graph capture on the harness.
// ===========================================================================
__global__ __launch_bounds__(256) void spectral_inter_kernel(
    const float* __restrict__ w_embed, const float* __restrict__ b_embed,
    const float* __restrict__ band_pos,
    const float* __restrict__ Wq, const float* __restrict__ bq,
    const float* __restrict__ Wk, const float* __restrict__ bk,
    const float* __restrict__ Wv, const float* __restrict__ bv,
    float* __restrict__ inter)
{
    const int g    = (blockIdx.x * 256 + threadIdx.x) >> 6;
    const int lane = threadIdx.x & 63;
    const int mc   = g >> 7;
    const int row  = g & 127;
    const int m = mc / 13, c = mc % 13;
    const float* M    = (m == 0) ? Wq : (m == 1) ? Wk : Wv;
    const float* bias = (m == 0) ? bq : (m == 1) ? bk : bv;

    const float2 mv = reinterpret_cast<const float2*>(M + row * D_MODEL)[lane];
    float2 vv;
    if (c == 0) {
        vv = reinterpret_cast<const float2*>(w_embed)[lane];
    } else {
        float2 be = reinterpret_cast<const float2*>(b_embed)[lane];
        float2 bp = reinterpret_cast<const float2*>(band_pos + (c - 1) * D_MODEL)[lane];
        vv = make_float2(be.x + bp.x, be.y + bp.y);
    }
    float s = fmaf(mv.x, vv.x, mv.y * vv.y);
    #pragma unroll
    for (int off = 32; off; off >>= 1) s += __shfl_xor(s, off, 64);
    if (lane == 0) {
        if (c) s += bias[row];
        inter[g] = s;
    }
}

__global__ __launch_bounds__(384) void spectral_consts_kernel(
    const float* __restrict__ inter, const float* __restrict__ Wo,
    float* __restrict__ consts)
{
    __shared__ float si[NROWS];
    __shared__ float swo[D_MODEL];
    const int t = threadIdx.x;
    for (int i = t; i < NROWS; i += 384) si[i] = inter[i];
    if (t < D_MODEL) swo[t] = Wo[t];
    __syncthreads();

    const int idx = t;
    if (idx >= NCONSTS) return;
    const float* qv = si;
    const float* kv = si + 13 * D_MODEL;
    const float* vv = si + 26 * D_MODEL;

    float s = 0.f;
    if (idx < 2) {
        int h = idx;
        #pragma unroll 8
        for (int d = 0; d < HDIM; ++d) s = fmaf(qv[h*HDIM+d], kv[h*HDIM+d], s);
        s *= LOGIT_SCALE;
    } else if (idx < 4) {
        int h = idx - 2;
        #pragma unroll 8
        for (int d = 0; d < HDIM; ++d) s = fmaf(vv[h*HDIM+d], swo[h*HDIM+d], s);
    } else if (idx < 28) {
        int i = idx - 4, h = i / NBANDS, k = i % NBANDS;
        const float* kc = kv + (1 + k) * D_MODEL;
        #pragma unroll 8
        for (int d = 0; d < HDIM; ++d) s = fmaf(qv[h*HDIM+d], kc[h*HDIM+d], s);
        s *= LOGIT_SCALE;
    } else if (idx < 52) {
        int i = idx - 28, h = i / NBANDS, q = i % NBANDS;
        const float* qc = qv + (1 + q) * D_MODEL;
        #pragma unroll 8
        for (int d = 0; d < HDIM; ++d) s = fmaf(qc[h*HDIM+d], kv[h*HDIM+d], s);
        s *= LOGIT_SCALE;
    } else if (idx < 76) {
        int i = idx - 52, h = i / NBANDS, k = i % NBANDS;
        const float* vc = vv + (1 + k) * D_MODEL;
        #pragma unroll 8
        for (int d = 0; d < HDIM; ++d) s = fmaf(vc[h*HDIM+d], swo[h*HDIM+d], s);
    } else {
        int i = idx - 76, h = i / (NBANDS*NBANDS);
        int q = (i / NBANDS) % NBANDS, k = i % NBANDS;
        const float* qc = qv + (1 + q) * D_MODEL;
        const float* kc = kv + (1 + k) * D_MODEL;
        #pragma unroll 8
        for (int d = 0; d < HDIM; ++d) s = fmaf(qc[h*HDIM+d], kc[h*HDIM+d], s);
        s *= LOGIT_SCALE;
    }
    consts[idx] = s;
}

__global__ __launch_bounds__(256) void spectral_main_kernel(
    const float* __restrict__ x, const float* __restrict__ bo,
    const float* __restrict__ consts, float* __restrict__ out, int n_total)
{
    __shared__ float sc[NCONSTS];
    const int t = threadIdx.x;
    for (int i = t; i < NCONSTS; i += 256) sc[i] = consts[i];
    __syncthreads();

    const int tid = blockIdx.x * 256 + t;
    if (tid >= n_total) return;

    const unsigned n = (unsigned)tid / 12u;
    const int q = tid - (int)n * 12;

    const float4* xin = reinterpret_cast<const float4*>(x + (size_t)n * NBANDS);
    float4 p0 = xin[0], p1 = xin[1], p2 = xin[2];
    float xb[NBANDS] = {p0.x,p0.y,p0.z,p0.w, p1.x,p1.y,p1.z,p1.w, p2.x,p2.y,p2.z,p2.w};
    const float xq = x[tid];

    float acc = bo[0];
    #pragma unroll
    for (int h = 0; h < NHEADS; ++h) {
        const float a = sc[h];
        const float e = sc[2 + h];
        const float* u  = &sc[4  + h * NBANDS];
        const float vq  = sc[28 + h * NBANDS + q];
        const float* g  = &sc[52 + h * NBANDS];
        const float* wq = &sc[76 + h * NBANDS * NBANDS + q * NBANDS];
        const float coef = fmaf(a, xq, vq);
        float den = 0.f, num = 0.f;
        #pragma unroll
        for (int k = 0; k < NBANDS; ++k) {
            float sv = fmaf(coef, xb[k], fmaf(u[k], xq, wq[k]));
            float p  = __builtin_amdgcn_exp2f(sv);
            den += p;
            num  = fmaf(p, fmaf(e, xb[k], g[k]), num);
        }
        acc = fmaf(num, __builtin_amdgcn_rcpf(den), acc);
    }

    out[tid] = xq + acc;
}

extern "C" void kernel_launch(void* const* d_in, const int* in_sizes, int n_in,
                              void* d_out, int out_size, void* d_ws, size_t ws_size,
                              hipStream_t stream)
{
    const float* x  = (const float*)d_in[0];
    const float* we = (const float*)d_in[1];
    const float* be = (const float*)d_in[2];
    const float* bp = (const float*)d_in[3];
    const float* Wq = (const float*)d_in[4];
    const float* bq = (const float*)d_in[5];
    const float* Wk = (const float*)d_in[6];
    const float* bk = (const float*)d_in[7];
    const float* Wv = (const float*)d_in[8];
    const float* bv = (const float*)d_in[9];
    const float* Wo = (const float*)d_in[10];
    const float* bo = (const float*)d_in[11];
    float* out    = (float*)d_out;
    float* ws     = (float*)d_ws;              // inter[4992] + consts[364]

    int n_total = in_sizes[0];                 // tokens * 12

    // Resolve cooperative grid size once (pure driver query, capture-safe).
    static int coop_grid = -2;                 // -2 = uninitialized, 0 = disabled
    if (coop_grid == -2) {
        int nb = 0;
        hipError_t e = hipOccupancyMaxActiveBlocksPerMultiprocessor(
            &nb, spectral_fused_kernel, BLOCK, 0);
        if (e == hipSuccess && nb >= 1) {
            long g = (long)nb * 256;           // 256 CUs on MI355X
            if (g > 1024) g = 1024;            // 4 blocks/CU target
            coop_grid = (int)g;
        } else {
            coop_grid = 0;
        }
    }

    bool launched = false;
    if (coop_grid > 0) {
        void* args[] = {
            (void*)&x,  (void*)&we, (void*)&be, (void*)&bp,
            (void*)&Wq, (void*)&bq, (void*)&Wk, (void*)&bk,
            (void*)&Wv, (void*)&bv, (void*)&Wo, (void*)&bo,
            (void*)&ws, (void*)&out, (void*)&n_total
        };
        hipError_t err = hipLaunchCooperativeKernel(
            spectral_fused_kernel, dim3(coop_grid), dim3(BLOCK), args, 0, stream);
        if (err == hipSuccess) {
            launched = true;
        } else {
            coop_grid = 0;   // don't retry on later calls
        }
    }

    if (!launched) {
        float* inter  = ws;
        float* consts = ws + NROWS;
        hipLaunchKernelGGL(spectral_inter_kernel, dim3(NROWS / 4), dim3(256), 0, stream,
                           we, be, bp, Wq, bq, Wk, bk, Wv, bv, inter);
        hipLaunchKernelGGL(spectral_consts_kernel, dim3(1), dim3(384), 0, stream,
                           inter, Wo, consts);
        hipLaunchKernelGGL(spectral_main_kernel,
                           dim3((n_total + 255) / 256), dim3(256), 0, stream,
                           x, bo, consts, out, n_total);
    }
}

// Round 2
// 93.843 us; speedup vs baseline: 2.6816x; 2.6816x over previous
//
#include <hip/hip_runtime.h>

#define D_MODEL 128
#define NBANDS 12
#define NHEADS 2
#define HDIM 64
#define NCONSTS 364   // a[2] e[2] u[24] v[24] g[24] w[288]
#define NROWS (39 * D_MODEL)   // 4992 projected-row dot products
#define NBLK_MAIN 512          // 2 blocks/CU, grid-stride main loop
// softmax logit scale with log2(e) pre-folded: exp(x*0.125) == exp2(x*0.18033688)
#define LOGIT_SCALE 0.18033688011112042f

// ---------------------------------------------------------------------------
// Kernel A (unchanged, proven): one WAVE per output row (1248 blocks).
//   inter[(m*13 + c)*128 + row], m in {0=q,1=k,2=v}
//   c==0  -> M @ w_embed                    (no bias)
//   c>=1  -> M @ (b_embed + band_pos[c-1]) + bias
// ---------------------------------------------------------------------------
__global__ __launch_bounds__(256) void spectral_inter_kernel(
    const float* __restrict__ w_embed, const float* __restrict__ b_embed,
    const float* __restrict__ band_pos,
    const float* __restrict__ Wq, const float* __restrict__ bq,
    const float* __restrict__ Wk, const float* __restrict__ bk,
    const float* __restrict__ Wv, const float* __restrict__ bv,
    float* __restrict__ inter)
{
    const int g    = (blockIdx.x * 256 + threadIdx.x) >> 6;  // row id 0..4991
    const int lane = threadIdx.x & 63;
    const int mc   = g >> 7;          // 0..38 (wave-uniform)
    const int row  = g & 127;
    const int m = mc / 13, c = mc % 13;
    const float* M    = (m == 0) ? Wq : (m == 1) ? Wk : Wv;
    const float* bias = (m == 0) ? bq : (m == 1) ? bk : bv;

    const float2 mv = reinterpret_cast<const float2*>(M + row * D_MODEL)[lane];
    float2 vv;
    if (c == 0) {
        vv = reinterpret_cast<const float2*>(w_embed)[lane];
    } else {
        float2 be = reinterpret_cast<const float2*>(b_embed)[lane];
        float2 bp = reinterpret_cast<const float2*>(band_pos + (c - 1) * D_MODEL)[lane];
        vv = make_float2(be.x + bp.x, be.y + bp.y);
    }
    float s = fmaf(mv.x, vv.x, mv.y * vv.y);
    #pragma unroll
    for (int off = 32; off; off >>= 1) s += __shfl_xor(s, off, 64);
    if (lane == 0) {
        if (c) s += bias[row];
        inter[g] = s;
    }
}

// ---------------------------------------------------------------------------
// Kernel C': consts (per-block redundant, from L2-hot inter) + main loop.
//   Eliminates the old single-block kernel B and one launch boundary.
//   consts layout in sc[]: a[2] e[2] u[2][12] v[2][12] g[2][12] w[2][12][12]
//   a,u,v,w carry LOGIT_SCALE; e,g plain.
// ---------------------------------------------------------------------------
__device__ __forceinline__ float dot64(const float* __restrict__ a,
                                       const float* __restrict__ b)
{
    const float2* a2 = reinterpret_cast<const float2*>(a);
    const float2* b2 = reinterpret_cast<const float2*>(b);
    float s = 0.f;
    #pragma unroll
    for (int i = 0; i < 32; ++i) {
        const float2 x = a2[i], y = b2[i];
        s = fmaf(x.x, y.x, s);
        s = fmaf(x.y, y.y, s);
    }
    return s;
}

__global__ __launch_bounds__(256) void spectral_main_kernel(
    const float* __restrict__ inter, const float* __restrict__ Wo,
    const float* __restrict__ x, const float* __restrict__ bo,
    float* __restrict__ out, int n_total)
{
    __shared__ float sc[NCONSTS];
    const int t = threadIdx.x;

    // ---- derive the 364 closed-form constants (redundant per block) ----
    {
        const float* qv = inter;                  // [13][128]: qw, qc[0..11]
        const float* kv = inter + 13 * D_MODEL;   // kw, kc[0..11]
        const float* vv = inter + 26 * D_MODEL;   // vw, vc[0..11]
        for (int idx = t; idx < NCONSTS; idx += 256) {
            float s;
            if (idx < 2) {                                   // a_h
                s = dot64(qv + idx * HDIM, kv + idx * HDIM) * LOGIT_SCALE;
            } else if (idx < 4) {                            // e_h (no scale)
                const int h = idx - 2;
                s = dot64(vv + h * HDIM, Wo + h * HDIM);
            } else if (idx < 28) {                           // u_h[k]
                const int i = idx - 4, h = i / NBANDS, k = i - h * NBANDS;
                s = dot64(qv + h * HDIM,
                          kv + (1 + k) * D_MODEL + h * HDIM) * LOGIT_SCALE;
            } else if (idx < 52) {                           // v_h[q]
                const int i = idx - 28, h = i / NBANDS, q = i - h * NBANDS;
                s = dot64(qv + (1 + q) * D_MODEL + h * HDIM,
                          kv + h * HDIM) * LOGIT_SCALE;
            } else if (idx < 76) {                           // g_h[k] (no scale)
                const int i = idx - 52, h = i / NBANDS, k = i - h * NBANDS;
                s = dot64(vv + (1 + k) * D_MODEL + h * HDIM, Wo + h * HDIM);
            } else {                                         // w_h[q][k]
                const int i = idx - 76, h = i / (NBANDS * NBANDS);
                const int r = i - h * NBANDS * NBANDS;
                const int q = r / NBANDS, k = r - q * NBANDS;
                s = dot64(qv + (1 + q) * D_MODEL + h * HDIM,
                          kv + (1 + k) * D_MODEL + h * HDIM) * LOGIT_SCALE;
            }
            sc[idx] = s;
        }
    }
    __syncthreads();

    // ---- main loop: one thread per (token, q), grid-strided ----
    const float bo0  = bo[0];
    const int stride = (int)gridDim.x * 256;
    for (int tid = (int)blockIdx.x * 256 + t; tid < n_total; tid += stride) {
        const unsigned n = (unsigned)tid / 12u;   // magic-mul div
        const int q = tid - (int)n * 12;

        const float4* xin = reinterpret_cast<const float4*>(x + (size_t)n * NBANDS);
        const float4 p0 = xin[0], p1 = xin[1], p2 = xin[2];
        const float xb[NBANDS] = {p0.x,p0.y,p0.z,p0.w, p1.x,p1.y,p1.z,p1.w, p2.x,p2.y,p2.z,p2.w};
        const float xq = x[tid];   // == xb[q] without dynamic reg indexing

        float acc = bo0;
        #pragma unroll
        for (int h = 0; h < NHEADS; ++h) {
            const float a = sc[h];
            const float e = sc[2 + h];
            const float* u  = &sc[4  + h * NBANDS];
            const float vq  = sc[28 + h * NBANDS + q];
            const float* g  = &sc[52 + h * NBANDS];
            const float* wq = &sc[76 + h * NBANDS * NBANDS + q * NBANDS];
            const float coef = fmaf(a, xq, vq);
            float den = 0.f, num = 0.f;
            #pragma unroll
            for (int k = 0; k < NBANDS; ++k) {
                const float sv = fmaf(coef, xb[k], fmaf(u[k], xq, wq[k]));  // log2-domain logit
                const float p  = __builtin_amdgcn_exp2f(sv);
                den += p;
                num  = fmaf(p, fmaf(e, xb[k], g[k]), num);
            }
            acc = fmaf(num, __builtin_amdgcn_rcpf(den), acc);
        }
        out[tid] = xq + acc;
    }
}

extern "C" void kernel_launch(void* const* d_in, const int* in_sizes, int n_in,
                              void* d_out, int out_size, void* d_ws, size_t ws_size,
                              hipStream_t stream)
{
    const float* x  = (const float*)d_in[0];
    const float* we = (const float*)d_in[1];
    const float* be = (const float*)d_in[2];
    const float* bp = (const float*)d_in[3];
    const float* Wq = (const float*)d_in[4];
    const float* bq = (const float*)d_in[5];
    const float* Wk = (const float*)d_in[6];
    const float* bk = (const float*)d_in[7];
    const float* Wv = (const float*)d_in[8];
    const float* bv = (const float*)d_in[9];
    const float* Wo = (const float*)d_in[10];
    const float* bo = (const float*)d_in[11];
    float* out   = (float*)d_out;
    float* inter = (float*)d_ws;               // 4992 floats

    const int n_total = in_sizes[0];           // tokens * 12

    // 4992 rows, one wave each, 4 waves/block -> 1248 blocks
    hipLaunchKernelGGL(spectral_inter_kernel, dim3(NROWS / 4), dim3(256), 0, stream,
                       we, be, bp, Wq, bq, Wk, bk, Wv, bv, inter);
    // consts (per-block) + main, grid-strided: 512 blocks = 2/CU
    hipLaunchKernelGGL(spectral_main_kernel, dim3(NBLK_MAIN), dim3(256), 0, stream,
                       inter, Wo, x, bo, out, n_total);
}